// Round 7
// baseline (668.828 us; speedup 1.0000x reference)
//
#include <hip/hip_runtime.h>
#include <hip/hip_bf16.h>

typedef short s16x8 __attribute__((ext_vector_type(8)));
typedef float f32x4 __attribute__((ext_vector_type(4)));

#define CAPB 640     // per-bucket segment capacity (mean 410 = lambda+11sigma)
#define SB   64      // edge-slice blocks (histogram + scatter)
#define NBMAX 4096   // max coarse buckets (N <= 262144)

static __device__ inline unsigned short f2bf(float f) {
    __hip_bfloat16 h = __float2bfloat16(f);
    return *reinterpret_cast<unsigned short*>(&h);
}
static __device__ inline float bf2f(unsigned short u) {
    return __uint_as_float((unsigned int)u << 16);
}

// ---------- K1: wT hi/lo split + per-slice coarse histogram (LDS) --------
__global__ __launch_bounds__(256) void hist_kernel(
    const float* __restrict__ w, const int* __restrict__ B,
    unsigned short* __restrict__ wTh, unsigned short* __restrict__ wTl,
    int* __restrict__ part, int NB, int E, int EPB)
{
    __shared__ int hist[NBMAX];
    const int b = blockIdx.x, tid = threadIdx.x;

    int i = b * 256 + tid;                 // SB*256 = 16384 = wT elements
    if (i < 16384) {
        int n = i >> 7, k = i & 127;
        float v = w[k * 128 + n];
        unsigned short hi = f2bf(v);
        wTh[i] = hi;
        wTl[i] = f2bf(v - bf2f(hi));
    }

    for (int g = tid; g < NB; g += 256) hist[g] = 0;
    __syncthreads();
    const int e0 = b * EPB, e1 = min(E, e0 + EPB);
    for (int e = e0 + tid; e < e1; e += 256)
        atomicAdd(&hist[B[e] >> 6], 1);
    __syncthreads();
    for (int g = tid; g < NB; g += 256)
        part[g * SB + b] = hist[g];
}

// ---------- K2: per-bucket 64-lane prefix scan -> cursor bases -----------
__global__ __launch_bounds__(256) void scan_kernel(
    const int* __restrict__ part, int* __restrict__ offT,
    int* __restrict__ tot, int NB)
{
    const int g    = blockIdx.x * 4 + (threadIdx.x >> 6);
    const int lane = threadIdx.x & 63;
    if (g >= NB) return;
    int v = part[g * SB + lane];           // SB == 64 == wavefront
    int incl = v;
    #pragma unroll
    for (int s = 1; s < 64; s <<= 1) {
        int t = __shfl_up(incl, s);
        if (lane >= s) incl += t;
    }
    offT[lane * NB + g] = g * CAPB + (incl - v);
    if (lane == 63) tot[g] = incl;
}

// ---------- K3: scatter (blocks [0,SB)) + GEMM X@w -> Yh (rest) ----------
// Scatter: LDS cursors + LDS atomics, bucket-clustered stores of packed
// (a | (d&63)<<26). NO device atomics anywhere in the pipeline.
// GEMM: bf16x3; Yh stored column-PERMUTED pos=2*(col&63)+(col>>6) so the
// gather's single dword load covers natural cols {c, c+64}.
__global__ __launch_bounds__(256) void gemsc_kernel(
    const float* __restrict__ X, const int* __restrict__ A,
    const int* __restrict__ B, const unsigned short* __restrict__ wTh,
    const unsigned short* __restrict__ wTl, const int* __restrict__ offT,
    unsigned int* __restrict__ packed, unsigned short* __restrict__ Yh,
    int N, int E, int EPB, int NB)
{
    __shared__ int cur[NBMAX];
    const int tid = threadIdx.x;

    if (blockIdx.x < SB) {
        const int b = blockIdx.x;
        for (int g = tid; g < NB; g += 256) cur[g] = offT[b * NB + g];
        __syncthreads();
        const int e0 = b * EPB, e1 = min(E, e0 + EPB);
        for (int e = e0 + tid; e < e1; e += 256) {
            int a = A[e], d = B[e];
            int g = d >> 6;
            int pos = atomicAdd(&cur[g], 1);           // LDS atomic
            if (pos < (g + 1) * CAPB)                  // overflow: ~impossible
                packed[pos] = (unsigned int)a | ((unsigned int)(d & 63) << 26);
        }
        return;
    }

    // ---- GEMM tile: 64 rows/block, 4 waves x 16 rows ----
    const int gb   = blockIdx.x - SB;
    const int u    = tid >> 6;
    const int lane = tid & 63;
    const int m    = lane & 15;
    const int q    = lane >> 4;
    const int r0   = gb * 64;
    const int row  = r0 + u * 16 + m;
    const int rldr = (row < N) ? row : (N - 1);   // clamp: dup load, store guarded

    f32x4 acc[8] = {};
    #pragma unroll
    for (int s = 0; s < 4; ++s) {
        const float* xr = X + (size_t)rldr * 128 + s * 32 + q * 8;
        float4 x0 = *(const float4*)xr;
        float4 x1 = *(const float4*)(xr + 4);
        float xv[8] = {x0.x, x0.y, x0.z, x0.w, x1.x, x1.y, x1.z, x1.w};
        s16x8 ahi, alo;
        #pragma unroll
        for (int j = 0; j < 8; ++j) {
            unsigned short h = f2bf(xv[j]);
            ahi[j] = (short)h;
            alo[j] = (short)f2bf(xv[j] - bf2f(h));
        }
        #pragma unroll
        for (int c = 0; c < 8; ++c) {
            const size_t wo = (size_t)(c * 16 + m) * 128 + s * 32 + q * 8;
            s16x8 bh = *(const s16x8*)&wTh[wo];
            s16x8 bl = *(const s16x8*)&wTl[wo];
            acc[c] = __builtin_amdgcn_mfma_f32_16x16x32_bf16(ahi, bh, acc[c], 0, 0, 0);
            acc[c] = __builtin_amdgcn_mfma_f32_16x16x32_bf16(alo, bh, acc[c], 0, 0, 0);
            acc[c] = __builtin_amdgcn_mfma_f32_16x16x32_bf16(ahi, bl, acc[c], 0, 0, 0);
        }
    }

    const int r0g = r0 + u * 16 + q * 4;
    #pragma unroll
    for (int c = 0; c < 8; ++c) {
        int col = c * 16 + m;
        int pos = 2 * (col & 63) + (col >> 6);         // permuted position
        #pragma unroll
        for (int r = 0; r < 4; ++r) {
            int orow = r0g + r;
            if (orow < N)
                Yh[(size_t)orow * 128 + pos] = f2bf(acc[c][r]);
        }
    }
}

// ---------- K4: per-bucket tile gather, MLP-restored ---------------------
// r6 lesson: 1 edge/wave/iter = 2 rows in flight -> 484us latency wall.
// Now: each wave takes a contiguous chunk, loads 64 packed entries in ONE
// coalesced per-lane load, then per sub-batch issues 16 independent
// full-wave row-gathers (16 VMEM in flight/wave) BEFORE any accumulate.
// Accumulate guard (sub+j < nb) is wave-uniform; clamped dup loads are
// never added. LDS f32 atomics handle intra-block dest collisions.
__global__ __launch_bounds__(512) void tile_gather_kernel(
    const unsigned int* __restrict__ packed, const int* __restrict__ tot,
    const unsigned short* __restrict__ Yh, const float* __restrict__ b,
    float* __restrict__ out, int N)
{
    __shared__ float tile[64][129];
    const int g    = blockIdx.x;
    const int tid  = threadIdx.x;
    const int wv   = tid >> 6;
    const int lane = tid & 63;

    for (int i = tid; i < 64 * 129; i += 512)
        (&tile[0][0])[i] = 0.f;
    __syncthreads();

    const int nseg = min(tot[g], CAPB);
    if (nseg > 0) {
        const unsigned int* seg = packed + (size_t)g * CAPB;
        const int per = (nseg + 7) >> 3;               // per-wave chunk
        const int s0  = wv * per;
        const int s1  = min(nseg, s0 + per);
        for (int base = s0; base < s1; base += 64) {
            const int avail = s1 - base;               // > 0
            unsigned int pk = seg[base + ((lane < avail) ? lane : (avail - 1))];
            const int nb = (avail < 64) ? avail : 64;
            for (int sub = 0; sub < nb; sub += 16) {
                unsigned int pv[16];
                int rr[16];
                #pragma unroll
                for (int j = 0; j < 16; ++j) {
                    int sl = sub + j;
                    if (sl > nb - 1) sl = nb - 1;      // clamp: guarded below
                    unsigned int val = __shfl(pk, sl);
                    rr[j] = (int)(val >> 26);
                    int a = (int)(val & 0x03FFFFFF);
                    pv[j] = *(const unsigned int*)(Yh + (size_t)a * 128 + lane * 2);
                }
                #pragma unroll
                for (int j = 0; j < 16; ++j) {
                    if (sub + j < nb) {                // wave-uniform guard
                        atomicAdd(&tile[rr[j]][lane],
                                  __uint_as_float(pv[j] << 16));
                        atomicAdd(&tile[rr[j]][lane + 64],
                                  __uint_as_float(pv[j] & 0xFFFF0000u));
                    }
                }
            }
        }
    }
    __syncthreads();

    const int row = tid >> 3;                          // 64 rows x 8 threads
    const int cb  = (tid & 7) * 16;
    const int orow = g * 64 + row;
    if (orow < N) {
        #pragma unroll
        for (int k = 0; k < 4; ++k) {
            int col = cb + k * 4;
            float4 b4 = *(const float4*)(b + col);
            float4 o = { tile[row][col]     + b4.x, tile[row][col + 1] + b4.y,
                         tile[row][col + 2] + b4.z, tile[row][col + 3] + b4.w };
            *(float4*)(out + (size_t)orow * 128 + col) = o;
        }
    }
}

extern "C" void kernel_launch(void* const* d_in, const int* in_sizes, int n_in,
                              void* d_out, int out_size, void* d_ws, size_t ws_size,
                              hipStream_t stream) {
    const float* X = (const float*)d_in[0];
    const int*   A = (const int*)d_in[1];
    const int*   B = (const int*)d_in[2];
    const float* w = (const float*)d_in[3];
    const float* b = (const float*)d_in[4];
    float* out = (float*)d_out;

    const int N   = in_sizes[0] / 128;
    const int E   = in_sizes[1];
    const int NB  = (N + 63) >> 6;           // coarse buckets (<= NBMAX)
    const int EPB = (E + SB - 1) / SB;       // edges per slice block

    // ws: part[NB*SB] | offT[SB*NB] | tot[NB] | packed[NB*CAPB] |
    //     wTh 32KB | wTl 32KB | Yh[N*128 bf16]        (~30.5 MB total)
    char* wsb = (char*)d_ws;
    size_t off = 0;
    int* part = (int*)(wsb + off); off += (size_t)NB * SB * 4;
    int* offT = (int*)(wsb + off); off += (size_t)SB * NB * 4;
    int* tot  = (int*)(wsb + off); off += (size_t)NB * 4;
    off = (off + 255) & ~(size_t)255;
    unsigned int* packed = (unsigned int*)(wsb + off); off += (size_t)NB * CAPB * 4;
    unsigned short* wTh = (unsigned short*)(wsb + off); off += 32768;
    unsigned short* wTl = (unsigned short*)(wsb + off); off += 32768;
    unsigned short* Yh  = (unsigned short*)(wsb + off);

    hist_kernel<<<SB, 256, 0, stream>>>(w, B, wTh, wTl, part, NB, E, EPB);
    scan_kernel<<<(NB + 3) / 4, 256, 0, stream>>>(part, offT, tot, NB);
    gemsc_kernel<<<SB + (N + 63) / 64, 256, 0, stream>>>(
        X, A, B, wTh, wTl, offT, packed, Yh, N, E, EPB, NB);
    tile_gather_kernel<<<NB, 512, 0, stream>>>(packed, tot, Yh, b, out, N);
}

// Round 8
// 666.615 us; speedup vs baseline: 1.0033x; 1.0033x over previous
//
#include <hip/hip_runtime.h>
#include <hip/hip_bf16.h>

typedef short s16x8 __attribute__((ext_vector_type(8)));
typedef float f32x4 __attribute__((ext_vector_type(4)));

#define CAPB 640     // per-bucket segment capacity (mean 410 = lambda+11sigma)
#define SB   64      // edge-slice blocks (histogram + scatter)
#define NBMAX 4096   // max coarse buckets (N <= 262144)

static __device__ inline unsigned short f2bf(float f) {
    __hip_bfloat16 h = __float2bfloat16(f);
    return *reinterpret_cast<unsigned short*>(&h);
}
static __device__ inline float bf2f(unsigned short u) {
    return __uint_as_float((unsigned int)u << 16);
}

// ---------- K1: wT hi/lo split + per-slice coarse histogram (LDS) --------
__global__ __launch_bounds__(256) void hist_kernel(
    const float* __restrict__ w, const int* __restrict__ B,
    unsigned short* __restrict__ wTh, unsigned short* __restrict__ wTl,
    int* __restrict__ part, int NB, int E, int EPB)
{
    __shared__ int hist[NBMAX];
    const int b = blockIdx.x, tid = threadIdx.x;

    int i = b * 256 + tid;                 // SB*256 = 16384 = wT elements
    if (i < 16384) {
        int n = i >> 7, k = i & 127;
        float v = w[k * 128 + n];
        unsigned short hi = f2bf(v);
        wTh[i] = hi;
        wTl[i] = f2bf(v - bf2f(hi));
    }

    for (int g = tid; g < NB; g += 256) hist[g] = 0;
    __syncthreads();
    const int e0 = b * EPB, e1 = min(E, e0 + EPB);
    for (int e = e0 + tid; e < e1; e += 256)
        atomicAdd(&hist[B[e] >> 6], 1);
    __syncthreads();
    for (int g = tid; g < NB; g += 256)
        part[g * SB + b] = hist[g];
}

// ---------- K2: per-bucket 64-lane prefix scan -> cursor bases -----------
__global__ __launch_bounds__(256) void scan_kernel(
    const int* __restrict__ part, int* __restrict__ offT,
    int* __restrict__ tot, int NB)
{
    const int g    = blockIdx.x * 4 + (threadIdx.x >> 6);
    const int lane = threadIdx.x & 63;
    if (g >= NB) return;
    int v = part[g * SB + lane];           // SB == 64 == wavefront
    int incl = v;
    #pragma unroll
    for (int s = 1; s < 64; s <<= 1) {
        int t = __shfl_up(incl, s);
        if (lane >= s) incl += t;
    }
    offT[lane * NB + g] = g * CAPB + (incl - v);
    if (lane == 63) tot[g] = incl;
}

// ---------- K3: scatter (blocks [0,SB)) + GEMM X@w -> Yh (rest) ----------
// Scatter: LDS cursors + LDS atomics, bucket-clustered stores of packed
// (a | (d&63)<<26). NO device atomics anywhere in the pipeline.
// GEMM: bf16x3; Yh stored column-PERMUTED pos=2*(col&63)+(col>>6) so the
// gather's single dword load covers natural cols {c, c+64}.
__global__ __launch_bounds__(256) void gemsc_kernel(
    const float* __restrict__ X, const int* __restrict__ A,
    const int* __restrict__ B, const unsigned short* __restrict__ wTh,
    const unsigned short* __restrict__ wTl, const int* __restrict__ offT,
    unsigned int* __restrict__ packed, unsigned short* __restrict__ Yh,
    int N, int E, int EPB, int NB)
{
    __shared__ int cur[NBMAX];
    const int tid = threadIdx.x;

    if (blockIdx.x < SB) {
        const int b = blockIdx.x;
        for (int g = tid; g < NB; g += 256) cur[g] = offT[b * NB + g];
        __syncthreads();
        const int e0 = b * EPB, e1 = min(E, e0 + EPB);
        for (int e = e0 + tid; e < e1; e += 256) {
            int a = A[e], d = B[e];
            int g = d >> 6;
            int pos = atomicAdd(&cur[g], 1);           // LDS atomic
            if (pos < (g + 1) * CAPB)                  // overflow: ~impossible
                packed[pos] = (unsigned int)a | ((unsigned int)(d & 63) << 26);
        }
        return;
    }

    // ---- GEMM tile: 64 rows/block, 4 waves x 16 rows ----
    const int gb   = blockIdx.x - SB;
    const int u    = tid >> 6;
    const int lane = tid & 63;
    const int m    = lane & 15;
    const int q    = lane >> 4;
    const int r0   = gb * 64;
    const int row  = r0 + u * 16 + m;
    const int rldr = (row < N) ? row : (N - 1);   // clamp: dup load, store guarded

    f32x4 acc[8] = {};
    #pragma unroll
    for (int s = 0; s < 4; ++s) {
        const float* xr = X + (size_t)rldr * 128 + s * 32 + q * 8;
        float4 x0 = *(const float4*)xr;
        float4 x1 = *(const float4*)(xr + 4);
        float xv[8] = {x0.x, x0.y, x0.z, x0.w, x1.x, x1.y, x1.z, x1.w};
        s16x8 ahi, alo;
        #pragma unroll
        for (int j = 0; j < 8; ++j) {
            unsigned short h = f2bf(xv[j]);
            ahi[j] = (short)h;
            alo[j] = (short)f2bf(xv[j] - bf2f(h));
        }
        #pragma unroll
        for (int c = 0; c < 8; ++c) {
            const size_t wo = (size_t)(c * 16 + m) * 128 + s * 32 + q * 8;
            s16x8 bh = *(const s16x8*)&wTh[wo];
            s16x8 bl = *(const s16x8*)&wTl[wo];
            acc[c] = __builtin_amdgcn_mfma_f32_16x16x32_bf16(ahi, bh, acc[c], 0, 0, 0);
            acc[c] = __builtin_amdgcn_mfma_f32_16x16x32_bf16(alo, bh, acc[c], 0, 0, 0);
            acc[c] = __builtin_amdgcn_mfma_f32_16x16x32_bf16(ahi, bl, acc[c], 0, 0, 0);
        }
    }

    const int r0g = r0 + u * 16 + q * 4;
    #pragma unroll
    for (int c = 0; c < 8; ++c) {
        int col = c * 16 + m;
        int pos = 2 * (col & 63) + (col >> 6);         // permuted position
        #pragma unroll
        for (int r = 0; r < 4; ++r) {
            int orow = r0g + r;
            if (orow < N)
                Yh[(size_t)orow * 128 + pos] = f2bf(acc[c][r]);
        }
    }
}

// ---------- K4: per-bucket tile gather, schedule-pinned batches ----------
// r7 lesson: VGPR=32 proved the compiler folded the 16-deep load batch back
// into load->atomic->load (2 in flight, 500us). sched_barrier(0) fences pin
// the cluster: all 16 row-gathers ISSUE before the first ds_add, and the
// next batch's loads can't slide up into this batch's atomics. RA must keep
// 16 results live -> expect VGPR ~64 (that's the probe of the theory).
__global__ __launch_bounds__(512) void tile_gather_kernel(
    const unsigned int* __restrict__ packed, const int* __restrict__ tot,
    const unsigned short* __restrict__ Yh, const float* __restrict__ b,
    float* __restrict__ out, int N)
{
    __shared__ float tile[64][129];
    const int g    = blockIdx.x;
    const int tid  = threadIdx.x;
    const int wv   = tid >> 6;
    const int lane = tid & 63;

    for (int i = tid; i < 64 * 129; i += 512)
        (&tile[0][0])[i] = 0.f;
    __syncthreads();

    const int nseg = min(tot[g], CAPB);
    if (nseg > 0) {
        const unsigned int* seg = packed + (size_t)g * CAPB;
        const int per = (nseg + 7) >> 3;               // per-wave chunk
        const int s0  = wv * per;
        const int s1  = min(nseg, s0 + per);
        for (int base = s0; base < s1; base += 64) {
            const int avail = s1 - base;               // > 0
            unsigned int pk = seg[base + ((lane < avail) ? lane : (avail - 1))];
            const int nb = (avail < 64) ? avail : 64;
            for (int sub = 0; sub < nb; sub += 16) {
                unsigned int pv[16];
                int rr[16];
                #pragma unroll
                for (int j = 0; j < 16; ++j) {
                    int sl = sub + j;
                    if (sl > nb - 1) sl = nb - 1;      // clamp: guarded below
                    unsigned int val = __shfl(pk, sl);
                    rr[j] = (int)(val >> 26);
                    int a = (int)(val & 0x03FFFFFF);
                    pv[j] = *(const unsigned int*)(Yh + (size_t)a * 128 + lane * 2);
                }
                __builtin_amdgcn_sched_barrier(0);     // pin: 16 loads in flight
                #pragma unroll
                for (int j = 0; j < 16; ++j) {
                    if (sub + j < nb) {                // wave-uniform guard
                        atomicAdd(&tile[rr[j]][lane],
                                  __uint_as_float(pv[j] << 16));
                        atomicAdd(&tile[rr[j]][lane + 64],
                                  __uint_as_float(pv[j] & 0xFFFF0000u));
                    }
                }
                __builtin_amdgcn_sched_barrier(0);     // keep batches separate
            }
        }
    }
    __syncthreads();

    const int row = tid >> 3;                          // 64 rows x 8 threads
    const int cb  = (tid & 7) * 16;
    const int orow = g * 64 + row;
    if (orow < N) {
        #pragma unroll
        for (int k = 0; k < 4; ++k) {
            int col = cb + k * 4;
            float4 b4 = *(const float4*)(b + col);
            float4 o = { tile[row][col]     + b4.x, tile[row][col + 1] + b4.y,
                         tile[row][col + 2] + b4.z, tile[row][col + 3] + b4.w };
            *(float4*)(out + (size_t)orow * 128 + col) = o;
        }
    }
}

extern "C" void kernel_launch(void* const* d_in, const int* in_sizes, int n_in,
                              void* d_out, int out_size, void* d_ws, size_t ws_size,
                              hipStream_t stream) {
    const float* X = (const float*)d_in[0];
    const int*   A = (const int*)d_in[1];
    const int*   B = (const int*)d_in[2];
    const float* w = (const float*)d_in[3];
    const float* b = (const float*)d_in[4];
    float* out = (float*)d_out;

    const int N   = in_sizes[0] / 128;
    const int E   = in_sizes[1];
    const int NB  = (N + 63) >> 6;           // coarse buckets (<= NBMAX)
    const int EPB = (E + SB - 1) / SB;       // edges per slice block

    // ws: part[NB*SB] | offT[SB*NB] | tot[NB] | packed[NB*CAPB] |
    //     wTh 32KB | wTl 32KB | Yh[N*128 bf16]        (~30.5 MB total)
    char* wsb = (char*)d_ws;
    size_t off = 0;
    int* part = (int*)(wsb + off); off += (size_t)NB * SB * 4;
    int* offT = (int*)(wsb + off); off += (size_t)SB * NB * 4;
    int* tot  = (int*)(wsb + off); off += (size_t)NB * 4;
    off = (off + 255) & ~(size_t)255;
    unsigned int* packed = (unsigned int*)(wsb + off); off += (size_t)NB * CAPB * 4;
    unsigned short* wTh = (unsigned short*)(wsb + off); off += 32768;
    unsigned short* wTl = (unsigned short*)(wsb + off); off += 32768;
    unsigned short* Yh  = (unsigned short*)(wsb + off);

    hist_kernel<<<SB, 256, 0, stream>>>(w, B, wTh, wTl, part, NB, E, EPB);
    scan_kernel<<<(NB + 3) / 4, 256, 0, stream>>>(part, offT, tot, NB);
    gemsc_kernel<<<SB + (N + 63) / 64, 256, 0, stream>>>(
        X, A, B, wTh, wTl, offT, packed, Yh, N, E, EPB, NB);
    tile_gather_kernel<<<NB, 512, 0, stream>>>(packed, tot, Yh, b, out, N);
}

// Round 9
// 213.273 us; speedup vs baseline: 3.1360x; 3.1256x over previous
//
#include <hip/hip_runtime.h>
#include <hip/hip_bf16.h>

typedef short s16x8 __attribute__((ext_vector_type(8)));
typedef float f32x4 __attribute__((ext_vector_type(4)));

#define CAPB 640     // per-bucket segment capacity (mean 410 = lambda+11sigma)
#define SB   64      // edge-slice blocks (histogram + scatter)
#define NBMAX 4096   // max coarse buckets (N <= 262144)

static __device__ inline unsigned short f2bf(float f) {
    __hip_bfloat16 h = __float2bfloat16(f);
    return *reinterpret_cast<unsigned short*>(&h);
}
static __device__ inline float bf2f(unsigned short u) {
    return __uint_as_float((unsigned int)u << 16);
}

// ---------- K1: wT hi/lo split + per-slice coarse histogram (LDS) --------
__global__ __launch_bounds__(256) void hist_kernel(
    const float* __restrict__ w, const int* __restrict__ B,
    unsigned short* __restrict__ wTh, unsigned short* __restrict__ wTl,
    int* __restrict__ part, int NB, int E, int EPB)
{
    __shared__ int hist[NBMAX];
    const int b = blockIdx.x, tid = threadIdx.x;

    int i = b * 256 + tid;                 // SB*256 = 16384 = wT elements
    if (i < 16384) {
        int n = i >> 7, k = i & 127;
        float v = w[k * 128 + n];
        unsigned short hi = f2bf(v);
        wTh[i] = hi;
        wTl[i] = f2bf(v - bf2f(hi));
    }

    for (int g = tid; g < NB; g += 256) hist[g] = 0;
    __syncthreads();
    const int e0 = b * EPB, e1 = min(E, e0 + EPB);
    for (int e = e0 + tid; e < e1; e += 256)
        atomicAdd(&hist[B[e] >> 6], 1);
    __syncthreads();
    for (int g = tid; g < NB; g += 256)
        part[g * SB + b] = hist[g];
}

// ---------- K2: per-bucket 64-lane prefix scan -> cursor bases -----------
__global__ __launch_bounds__(256) void scan_kernel(
    const int* __restrict__ part, int* __restrict__ offT,
    int* __restrict__ tot, int NB)
{
    const int g    = blockIdx.x * 4 + (threadIdx.x >> 6);
    const int lane = threadIdx.x & 63;
    if (g >= NB) return;
    int v = part[g * SB + lane];           // SB == 64 == wavefront
    int incl = v;
    #pragma unroll
    for (int s = 1; s < 64; s <<= 1) {
        int t = __shfl_up(incl, s);
        if (lane >= s) incl += t;
    }
    offT[lane * NB + g] = g * CAPB + (incl - v);
    if (lane == 63) tot[g] = incl;
}

// ---------- K3: scatter (blocks [0,SB)) + GEMM X@w -> Yh (rest) ----------
// Scatter: LDS cursors + LDS int atomics (native), bucket-clustered stores
// of packed (a | (d&63)<<26). NO device atomics anywhere in the pipeline.
// GEMM: bf16x3; Yh stored column-PERMUTED pos=2*(col&63)+(col>>6) so the
// gather's single dword load covers natural cols {c, c+64}.
__global__ __launch_bounds__(256) void gemsc_kernel(
    const float* __restrict__ X, const int* __restrict__ A,
    const int* __restrict__ B, const unsigned short* __restrict__ wTh,
    const unsigned short* __restrict__ wTl, const int* __restrict__ offT,
    unsigned int* __restrict__ packed, unsigned short* __restrict__ Yh,
    int N, int E, int EPB, int NB)
{
    __shared__ int cur[NBMAX];
    const int tid = threadIdx.x;

    if (blockIdx.x < SB) {
        const int b = blockIdx.x;
        for (int g = tid; g < NB; g += 256) cur[g] = offT[b * NB + g];
        __syncthreads();
        const int e0 = b * EPB, e1 = min(E, e0 + EPB);
        for (int e = e0 + tid; e < e1; e += 256) {
            int a = A[e], d = B[e];
            int g = d >> 6;
            int pos = atomicAdd(&cur[g], 1);           // LDS int atomic (native)
            if (pos < (g + 1) * CAPB)                  // overflow: ~impossible
                packed[pos] = (unsigned int)a | ((unsigned int)(d & 63) << 26);
        }
        return;
    }

    // ---- GEMM tile: 64 rows/block, 4 waves x 16 rows ----
    const int gb   = blockIdx.x - SB;
    const int u    = tid >> 6;
    const int lane = tid & 63;
    const int m    = lane & 15;
    const int q    = lane >> 4;
    const int r0   = gb * 64;
    const int row  = r0 + u * 16 + m;
    const int rldr = (row < N) ? row : (N - 1);   // clamp: dup load, store guarded

    f32x4 acc[8] = {};
    #pragma unroll
    for (int s = 0; s < 4; ++s) {
        const float* xr = X + (size_t)rldr * 128 + s * 32 + q * 8;
        float4 x0 = *(const float4*)xr;
        float4 x1 = *(const float4*)(xr + 4);
        float xv[8] = {x0.x, x0.y, x0.z, x0.w, x1.x, x1.y, x1.z, x1.w};
        s16x8 ahi, alo;
        #pragma unroll
        for (int j = 0; j < 8; ++j) {
            unsigned short h = f2bf(xv[j]);
            ahi[j] = (short)h;
            alo[j] = (short)f2bf(xv[j] - bf2f(h));
        }
        #pragma unroll
        for (int c = 0; c < 8; ++c) {
            const size_t wo = (size_t)(c * 16 + m) * 128 + s * 32 + q * 8;
            s16x8 bh = *(const s16x8*)&wTh[wo];
            s16x8 bl = *(const s16x8*)&wTl[wo];
            acc[c] = __builtin_amdgcn_mfma_f32_16x16x32_bf16(ahi, bh, acc[c], 0, 0, 0);
            acc[c] = __builtin_amdgcn_mfma_f32_16x16x32_bf16(alo, bh, acc[c], 0, 0, 0);
            acc[c] = __builtin_amdgcn_mfma_f32_16x16x32_bf16(ahi, bl, acc[c], 0, 0, 0);
        }
    }

    const int r0g = r0 + u * 16 + q * 4;
    #pragma unroll
    for (int c = 0; c < 8; ++c) {
        int col = c * 16 + m;
        int pos = 2 * (col & 63) + (col >> 6);         // permuted position
        #pragma unroll
        for (int r = 0; r < 4; ++r) {
            int orow = r0g + r;
            if (orow < N)
                Yh[(size_t)orow * 128 + pos] = f2bf(acc[c][r]);
        }
    }
}

// ---------- K4: per-bucket gather, REGISTER accumulate -------------------
// r8 lesson: atomicAdd(float*) on LDS lowers to a ds_cmpst CAS retry loop
// (fp atomics aren't native-lowered like int) -> 1.28M wave-wide CAS loops
// = the 500us wall. r1's aggemm used the IDENTICAL load pattern with
// register accumulate and measured ~65us. So: build a tiny per-block CSR
// with native INT LDS atomics, then r1's proven inner loop: wave owns 8
// nodes (2 groups of 4), 4x8=32 independent {uniform LDS idx read ->
// full-row dword gather} chains in flight, accumulate in ax[]/ay[] regs,
// wave-uniform degree guard, coalesced dword stores + bias.
__global__ __launch_bounds__(512) void tile_gather_kernel(
    const unsigned int* __restrict__ packed, const int* __restrict__ tot,
    const unsigned short* __restrict__ Yh, const float* __restrict__ b,
    float* __restrict__ out, int N)
{
    __shared__ unsigned int eidx[CAPB];
    __shared__ int csr[CAPB];
    __shared__ int cnt64[64];
    __shared__ int base64[64];

    const int g    = blockIdx.x;
    const int tid  = threadIdx.x;
    const int wv   = tid >> 6;
    const int lane = tid & 63;

    // ---- zero counts + csr (csr zero-init kills garbage-index reads) ----
    if (tid < 64) cnt64[tid] = 0;
    for (int i = tid; i < CAPB; i += 512) csr[i] = 0;
    __syncthreads();

    const int nseg = min(tot[g], CAPB);
    // ---- stage packed + per-node histogram (native int LDS atomics) ----
    for (int e = tid; e < nseg; e += 512) {
        unsigned int v = packed[(size_t)g * CAPB + e];
        eidx[e] = v;
        atomicAdd(&cnt64[v >> 26], 1);
    }
    __syncthreads();
    // ---- exclusive scan of 64 counts (wave 0) ----
    if (tid < 64) {
        int v = cnt64[tid];
        int incl = v;
        #pragma unroll
        for (int s = 1; s < 64; s <<= 1) {
            int t = __shfl_up(incl, s);
            if (lane >= s) incl += t;
        }
        base64[tid] = incl - v;
        cnt64[tid] = 0;                    // reuse as scatter cursor
    }
    __syncthreads();
    // ---- scatter into per-node clustered csr ----
    for (int e = tid; e < nseg; e += 512) {
        unsigned int v = eidx[e];
        int r = (int)(v >> 26);
        int p = atomicAdd(&cnt64[r], 1);   // native ds_add_rtn_u32
        csr[base64[r] + p] = (int)(v & 0x03FFFFFF);
    }
    __syncthreads();

    // ---- r1-style gather: wave owns nodes wv*8..wv*8+7, 2 groups of 4 ----
    const float bb0 = b[lane];
    const float bb1 = b[lane + 64];
    #pragma unroll
    for (int grp = 0; grp < 2; ++grp) {
        int rl[4], cb[4], deg[4], last[4];
        #pragma unroll
        for (int t = 0; t < 4; ++t) {
            rl[t]   = wv * 8 + grp * 4 + t;          // local node 0..63
            cb[t]   = base64[rl[t]];
            deg[t]  = cnt64[rl[t]];
            last[t] = (deg[t] > 0) ? deg[t] - 1 : 0;
        }
        const int maxdg = max(max(deg[0], deg[1]), max(deg[2], deg[3]));
        const int maxch = (maxdg + 7) >> 3;
        float ax[4] = {0.f, 0.f, 0.f, 0.f};
        float ay[4] = {0.f, 0.f, 0.f, 0.f};
        #pragma unroll 1
        for (int ch = 0; ch < maxch; ++ch) {
            const int base = ch * 8;
            unsigned int p[4][8];
            #pragma unroll
            for (int t = 0; t < 4; ++t) {
                #pragma unroll
                for (int j = 0; j < 8; ++j) {
                    int sl = base + j;
                    if (sl > last[t]) sl = last[t];  // clamp: L1-hot dup
                    int s = csr[cb[t] + sl];         // wave-uniform broadcast
                    p[t][j] = *(const unsigned int*)(Yh + (size_t)s * 128 + lane * 2);
                }
            }
            #pragma unroll
            for (int t = 0; t < 4; ++t) {
                #pragma unroll
                for (int j = 0; j < 8; ++j)
                    if (base + j < deg[t]) {         // wave-uniform guard
                        ax[t] += __uint_as_float(p[t][j] << 16);
                        ay[t] += __uint_as_float(p[t][j] & 0xFFFF0000u);
                    }
            }
        }
        #pragma unroll
        for (int t = 0; t < 4; ++t) {
            int node = g * 64 + rl[t];
            if (node < N) {
                out[(size_t)node * 128 + lane]      = ax[t] + bb0;
                out[(size_t)node * 128 + 64 + lane] = ay[t] + bb1;
            }
        }
    }
}

extern "C" void kernel_launch(void* const* d_in, const int* in_sizes, int n_in,
                              void* d_out, int out_size, void* d_ws, size_t ws_size,
                              hipStream_t stream) {
    const float* X = (const float*)d_in[0];
    const int*   A = (const int*)d_in[1];
    const int*   B = (const int*)d_in[2];
    const float* w = (const float*)d_in[3];
    const float* b = (const float*)d_in[4];
    float* out = (float*)d_out;

    const int N   = in_sizes[0] / 128;
    const int E   = in_sizes[1];
    const int NB  = (N + 63) >> 6;           // coarse buckets (<= NBMAX)
    const int EPB = (E + SB - 1) / SB;       // edges per slice block

    // ws: part[NB*SB] | offT[SB*NB] | tot[NB] | packed[NB*CAPB] |
    //     wTh 32KB | wTl 32KB | Yh[N*128 bf16]        (~30.5 MB total)
    char* wsb = (char*)d_ws;
    size_t off = 0;
    int* part = (int*)(wsb + off); off += (size_t)NB * SB * 4;
    int* offT = (int*)(wsb + off); off += (size_t)SB * NB * 4;
    int* tot  = (int*)(wsb + off); off += (size_t)NB * 4;
    off = (off + 255) & ~(size_t)255;
    unsigned int* packed = (unsigned int*)(wsb + off); off += (size_t)NB * CAPB * 4;
    unsigned short* wTh = (unsigned short*)(wsb + off); off += 32768;
    unsigned short* wTl = (unsigned short*)(wsb + off); off += 32768;
    unsigned short* Yh  = (unsigned short*)(wsb + off);

    hist_kernel<<<SB, 256, 0, stream>>>(w, B, wTh, wTl, part, NB, E, EPB);
    scan_kernel<<<(NB + 3) / 4, 256, 0, stream>>>(part, offT, tot, NB);
    gemsc_kernel<<<SB + (N + 63) / 64, 256, 0, stream>>>(
        X, A, B, wTh, wTl, offT, packed, Yh, N, E, EPB, NB);
    tile_gather_kernel<<<NB, 512, 0, stream>>>(packed, tot, Yh, b, out, N);
}